// Round 13
// baseline (16748.643 us; speedup 1.0000x reference)
//
#include <hip/hip_runtime.h>
#include <cstddef>
#include <cstdint>

#define BB 256
#define SS 1024
#define VV 288
#define EE 100
#define HH 128
#define G4 512
#define CH 16
#define NCH (SS / CH)
#define NPIPE 24
#define NFC 1024

typedef _Float16 half8 __attribute__((ext_vector_type(8)));
typedef float f32x4 __attribute__((ext_vector_type(4)));
typedef float f32x2 __attribute__((ext_vector_type(2)));

__device__ __forceinline__ f32x2 exp2_2(f32x2 a) {
    f32x2 r;
    r[0] = __builtin_amdgcn_exp2f(a[0]);
    r[1] = __builtin_amdgcn_exp2f(a[1]);
    return r;
}
__device__ __forceinline__ f32x2 rcp_2(f32x2 a) {
    f32x2 r;
    r[0] = __builtin_amdgcn_rcpf(a[0]);
    r[1] = __builtin_amdgcn_rcpf(a[1]);
    return r;
}
__device__ __forceinline__ f32x2 vmin2(f32x2 a, float m) {
    f32x2 r;
    r[0] = fminf(a[0], m);
    r[1] = fminf(a[1], m);
    return r;
}

// LSTM elementwise for a row-pair; merged-rcp forms, total (inf-safe).
__device__ __forceinline__ f32x2 lstm_pair(
    f32x2 gi, f32x2 gf, f32x2 gg, f32x2 go, f32x2& cc)
{
    const float L1 = -1.4426950408889634f;   // -log2(e)
    const float L2 = -2.8853900817779268f;   // -2*log2(e)
    const f32x2 one = {1.0f, 1.0f};
    f32x2 ai = exp2_2(gi * L1);
    f32x2 bg = exp2_2(vmin2(gg * L2, 80.0f));
    f32x2 af = exp2_2(gf * L1);
    f32x2 sf = rcp_2(af + one);                       // sigmoid(f)
    f32x2 it = (one - bg) * rcp_2((ai + one) * (bg + one));
    cc = __builtin_elementwise_fma(sf, cc, it);       // c' = sf*c + it
    f32x2 dc = exp2_2(vmin2(cc * L2, 80.0f));
    f32x2 ao = exp2_2(go * L1);
    return (one - dc) * rcp_2((ao + one) * (dc + one));
}

// table[v][j] = bih0[j]+bhh0[j] + sum_e emb[v][e] * Wih0[j][e]   (fp32)
__global__ __launch_bounds__(512) void proj_kernel(
    const float* __restrict__ emb, const float* __restrict__ Wih0,
    const float* __restrict__ bih0, const float* __restrict__ bhh0,
    float* __restrict__ table)
{
    __shared__ float er[EE];
    const int v = blockIdx.x;
    const int j = threadIdx.x;
    for (int e = j; e < EE; e += 512) er[e] = emb[v * EE + e];
    __syncthreads();
    float acc = bih0[j] + bhh0[j];
    const float* wr = Wih0 + j * EE;
#pragma unroll 4
    for (int e = 0; e < EE; e++) acc = fmaf(er[e], wr[e], acc);
    table[v * G4 + j] = acc;
}

// ---- Fused 4-stage pipeline, 1024-thread blocks.
// Blocks 0..23: pipe (layer = bx>>3, two tiles per block: bt = (bx&7)*2+half,
//   half = tid>>9; per-wave code identical to the proven 512-thr version).
// Blocks 24..1047: FC head, one full timestep (256 rows) per block.
__global__ __launch_bounds__(1024)
__attribute__((amdgpu_waves_per_eu(4, 4)))
void lstm_pipe(const int* __restrict__ text, const float* __restrict__ table,
               const float* Whh0f,
               const float* Wih1f, const float* Whh1f,
               const float* __restrict__ bih1, const float* __restrict__ bhh1,
               const float* Wih2f, const float* Whh2f,
               const float* __restrict__ bih2, const float* __restrict__ bhh2,
               _Float16* hX, _Float16* hY,
               const float* __restrict__ fcW, const float* __restrict__ fcb,
               float* __restrict__ out, int* prog)
{
    __shared__ __align__(16) char shraw[147456];  // 2x64K tokL + 2x8K Hb | pfc
    const int tid = threadIdx.x;

    // ================= FC consumer blocks =================
    if (blockIdx.x >= NPIPE) {
        _Float16* pfc = (_Float16*)shraw;
        const int blk = blockIdx.x - NPIPE;       // timestep
        for (int i = tid; i < 36864; i += 1024) {
            const int e = i & 7;
            const int l = (i >> 3) & 63;
            const int f = i >> 9;
            const int kc = f & 3, nt = f >> 2;
            const int n = nt * 16 + (l & 15);
            const int k = kc * 32 + (l >> 4) * 8 + e;
            pfc[i] = (_Float16)fcW[n * HH + k];
        }
        __syncthreads();
        if (tid == 0) {
            for (int j = 0; j < 16; j++) {
                for (;;) {
                    int v = __hip_atomic_load(prog + 32 + j, __ATOMIC_RELAXED,
                                              __HIP_MEMORY_SCOPE_AGENT);
                    // unsigned: float-bit clobber after completion reads done
                    if ((unsigned)v > (unsigned)blk) break;
                    __builtin_amdgcn_s_sleep(64);
                }
            }
        }
        __syncthreads();
        {
            int v = __hip_atomic_load(prog + 32, __ATOMIC_ACQUIRE,
                                      __HIP_MEMORY_SCOPE_AGENT);
            asm volatile("" :: "v"(v));
        }
        const int wv = tid >> 6, l = tid & 63;
        const int colD = l & 15, qd = l >> 4;
        const size_t m0 = (size_t)blk * 256 + wv * 16;
        half8 a[4];
#pragma unroll
        for (int kc = 0; kc < 4; kc++)
            a[kc] = *(const half8*)(hX + (m0 + colD) * HH + kc * 32 + qd * 8);
        float fcb_r[18];
#pragma unroll
        for (int nt = 0; nt < 18; nt++) fcb_r[nt] = fcb[nt * 16 + colD];
#pragma unroll
        for (int nt = 0; nt < 18; nt++) {
            f32x4 acc = {0.f, 0.f, 0.f, 0.f};
#pragma unroll
            for (int kc = 0; kc < 4; kc++) {
                const half8 b =
                    *(const half8*)&pfc[(((nt * 4 + kc) << 6) + l) * 8];
                acc = __builtin_amdgcn_mfma_f32_16x16x32_f16(a[kc], b, acc,
                                                             0, 0, 0);
            }
#pragma unroll
            for (int r = 0; r < 4; r++)
                out[(m0 + 4 * qd + r) * VV + nt * 16 + colD] =
                    acc[r] + fcb_r[nt];
        }
        return;
    }

    // ================= LSTM pipeline blocks =================
    const int half = tid >> 9;           // which tile of the pair
    const int tsub = tid & 511;          // thread id within the tile program
    int* tokL = (int*)(shraw + half * 65536);            // 64 KB each (L0)
    typedef _Float16 HbRow[2048];
    HbRow* Hb = (HbRow*)(shraw + 131072 + half * 8192);  // 8 KB dbuf each
    const int w = tsub >> 6, l = tsub & 63;
    const int layer = blockIdx.x >> 3;
    const int bt = (blockIdx.x & 7) * 2 + half;
    const int B0 = bt * 16;
    const int colD = l & 15, qd = l >> 4;
    const int gcol = w * 16 + colD;

    const float* WhhF = (layer == 0) ? Whh0f : ((layer == 1) ? Whh1f : Whh2f);
    const float* WihF = (layer == 2) ? Wih2f : Wih1f;
    const float* bihp = (layer == 2) ? bih2 : bih1;
    const float* bhhp = (layer == 2) ? bhh2 : bhh1;
    const _Float16* xin = (layer == 1) ? hX : hY;
    _Float16* hout = (layer == 1) ? hY : hX;
    int* prog_src = prog + (layer - 1) * 16 + bt;
    int* prog_my  = prog + layer * 16 + bt;

    // Weight fragments straight from fp32 inputs (one-time)
    half8 whh[4][4], wih[4][4];
#pragma unroll
    for (int gt = 0; gt < 4; gt++)
#pragma unroll
        for (int kc = 0; kc < 4; kc++) {
            const int n = gt * 128 + gcol;
            const int k0 = kc * 32 + qd * 8;
            const float4 a0 = *(const float4*)(WhhF + (size_t)n * HH + k0);
            const float4 a1 = *(const float4*)(WhhF + (size_t)n * HH + k0 + 4);
            half8 hf;
            hf[0] = (_Float16)a0.x; hf[1] = (_Float16)a0.y;
            hf[2] = (_Float16)a0.z; hf[3] = (_Float16)a0.w;
            hf[4] = (_Float16)a1.x; hf[5] = (_Float16)a1.y;
            hf[6] = (_Float16)a1.z; hf[7] = (_Float16)a1.w;
            whh[gt][kc] = hf;
            if (layer) {
                const float4 b0 = *(const float4*)(WihF + (size_t)n * HH + k0);
                const float4 b1 = *(const float4*)(WihF + (size_t)n * HH + k0 + 4);
                half8 hg;
                hg[0] = (_Float16)b0.x; hg[1] = (_Float16)b0.y;
                hg[2] = (_Float16)b0.z; hg[3] = (_Float16)b0.w;
                hg[4] = (_Float16)b1.x; hg[5] = (_Float16)b1.y;
                hg[6] = (_Float16)b1.z; hg[7] = (_Float16)b1.w;
                wih[gt][kc] = hg;
            }
        }
    f32x4 bias_frag[4];
#pragma unroll
    for (int gt = 0; gt < 4; gt++) {
        float b = 0.0f;
        if (layer) {
            const int g = gt * 128 + gcol;
            b = bihp[g] + bhhp[g];
        }
        bias_frag[gt] = (f32x4){b, b, b, b};
    }
    if (layer == 0) {
        for (int kk = 0; kk < 32; kk++) {
            const int lin = kk * 512 + tsub;
            const int b = lin >> 10, t = lin & 1023;
            tokL[t * 16 + b] = text[(((size_t)B0 + b) << 10) | t];
        }
    }
    for (int i = tsub; i < 2048; i += 512) Hb[0][i] = (_Float16)0.0f;
    f32x2 c_acc0 = {0.f, 0.f}, c_acc1 = {0.f, 0.f};

    int rd_idx[4], wr_idx[4];
#pragma unroll
    for (int kc = 0; kc < 4; kc++)
        rd_idx[kc] = (colD * 128 + kc * 32 + qd * 8) ^ ((colD & 7) << 3);
#pragma unroll
    for (int r = 0; r < 4; r++) {
        const int rr = 4 * qd + r;
        wr_idx[r] = (rr * 128 + gcol) ^ ((rr & 7) << 3);
    }
    _Float16* houtp = hout + ((size_t)B0 + 4 * qd) * HH + gcol;
    __syncthreads();

    auto wait_src = [&](int target) {
        int v = __hip_atomic_load(prog_src, __ATOMIC_RELAXED,
                                  __HIP_MEMORY_SCOPE_AGENT);
        while (v < target) {
            __builtin_amdgcn_s_sleep(8);
            v = __hip_atomic_load(prog_src, __ATOMIC_RELAXED,
                                  __HIP_MEMORY_SCOPE_AGENT);
        }
        v = __hip_atomic_load(prog_src, __ATOMIC_ACQUIRE,
                              __HIP_MEMORY_SCOPE_AGENT);
        asm volatile("" :: "v"(v));
    };
    auto signal = [&](int c) {
        asm volatile("s_waitcnt vmcnt(0)" ::: "memory");
        __builtin_amdgcn_s_barrier();
        if (tsub == 0) {                 // one signaler per tile (tid 0 / 512)
            __threadfence();
            __hip_atomic_store(prog_my, (c + 1) * CH, __ATOMIC_RELEASE,
                               __HIP_MEMORY_SCOPE_AGENT);
        }
    };
    auto finish = [&](f32x4 (&p)[4], f32x4 (&q)[4], int nxt) {
        f32x4 acc[4];
#pragma unroll
        for (int gt = 0; gt < 4; gt++) acc[gt] = p[gt] + q[gt];
        {
            f32x2 gi = {acc[0][0], acc[0][1]};
            f32x2 gf = {acc[1][0], acc[1][1]};
            f32x2 gg = {acc[2][0], acc[2][1]};
            f32x2 go = {acc[3][0], acc[3][1]};
            f32x2 hv = lstm_pair(gi, gf, gg, go, c_acc0);
            const _Float16 h0 = (_Float16)hv[0];
            const _Float16 h1 = (_Float16)hv[1];
            Hb[nxt][wr_idx[0]] = h0;
            Hb[nxt][wr_idx[1]] = h1;
            houtp[0 * HH] = h0;
            houtp[1 * HH] = h1;
        }
        {
            f32x2 gi = {acc[0][2], acc[0][3]};
            f32x2 gf = {acc[1][2], acc[1][3]};
            f32x2 gg = {acc[2][2], acc[2][3]};
            f32x2 go = {acc[3][2], acc[3][3]};
            f32x2 hv = lstm_pair(gi, gf, gg, go, c_acc1);
            const _Float16 h2 = (_Float16)hv[0];
            const _Float16 h3 = (_Float16)hv[1];
            Hb[nxt][wr_idx[2]] = h2;
            Hb[nxt][wr_idx[3]] = h3;
            houtp[2 * HH] = h2;
            houtp[3 * HH] = h3;
        }
        houtp += BB * HH;
        asm volatile("s_waitcnt lgkmcnt(0)" ::: "memory");
        __builtin_amdgcn_s_barrier();
    };

    if (layer == 0) {
        f32x4 xgA[4], xgB[4];
        {
            const int4 tk0 = *(const int4*)&tokL[4 * qd];
            const float* g0 = table + (size_t)tk0.x * G4 + gcol;
            const float* g1 = table + (size_t)tk0.y * G4 + gcol;
            const float* g2 = table + (size_t)tk0.z * G4 + gcol;
            const float* g3 = table + (size_t)tk0.w * G4 + gcol;
#pragma unroll
            for (int gt = 0; gt < 4; gt++) {
                xgA[gt][0] = g0[gt * 128];
                xgA[gt][1] = g1[gt * 128];
                xgA[gt][2] = g2[gt * 128];
                xgA[gt][3] = g3[gt * 128];
            }
        }
        auto step0 = [&](int T, int cur, f32x4 (&xgc)[4], f32x4 (&xgn)[4]) {
            half8 a_h[4];
#pragma unroll
            for (int kc = 0; kc < 4; kc++)
                a_h[kc] = *(const half8*)&Hb[cur][rd_idx[kc]];
            const int Tn = (T + 1 < SS) ? T + 1 : T;
            const int4 tkn = *(const int4*)&tokL[Tn * 16 + 4 * qd];
            f32x4 p[4], q[4];
#pragma unroll
            for (int gt = 0; gt < 4; gt++) {
                f32x4 t = __builtin_amdgcn_mfma_f32_16x16x32_f16(
                    a_h[0], whh[gt][0], xgc[gt], 0, 0, 0);
                p[gt] = __builtin_amdgcn_mfma_f32_16x16x32_f16(
                    a_h[1], whh[gt][1], t, 0, 0, 0);
                f32x4 u = __builtin_amdgcn_mfma_f32_16x16x32_f16(
                    a_h[2], whh[gt][2], (f32x4){0.f, 0.f, 0.f, 0.f}, 0, 0, 0);
                q[gt] = __builtin_amdgcn_mfma_f32_16x16x32_f16(
                    a_h[3], whh[gt][3], u, 0, 0, 0);
            }
            {
                const float* g0 = table + (size_t)tkn.x * G4 + gcol;
                const float* g1 = table + (size_t)tkn.y * G4 + gcol;
                const float* g2 = table + (size_t)tkn.z * G4 + gcol;
                const float* g3 = table + (size_t)tkn.w * G4 + gcol;
#pragma unroll
                for (int gt = 0; gt < 4; gt++) {
                    xgn[gt][0] = g0[gt * 128];
                    xgn[gt][1] = g1[gt * 128];
                    xgn[gt][2] = g2[gt * 128];
                    xgn[gt][3] = g3[gt * 128];
                }
            }
            finish(p, q, cur ^ 1);
        };
        for (int c = 0; c < NCH; c++) {
            for (int tt = 0; tt < CH; tt += 2) {
                step0(c * CH + tt,     0, xgA, xgB);
                step0(c * CH + tt + 1, 1, xgB, xgA);
            }
            signal(c);
        }
    } else {
        wait_src(2 * CH);
        const _Float16* xbase = xin + ((size_t)B0 + colD) * HH + qd * 8;
        half8 xcur[4];
        f32x4 accXA[4], accXB[4];
#pragma unroll
        for (int kc = 0; kc < 4; kc++)
            xcur[kc] = *(const half8*)(xbase + (size_t)0 * BB * HH + kc * 32);
#pragma unroll
        for (int gt = 0; gt < 4; gt++) {
            f32x4 t = bias_frag[gt];
#pragma unroll
            for (int kc = 0; kc < 4; kc++)
                t = __builtin_amdgcn_mfma_f32_16x16x32_f16(
                    xcur[kc], wih[gt][kc], t, 0, 0, 0);
            accXA[gt] = t;
        }
#pragma unroll
        for (int kc = 0; kc < 4; kc++)
            xcur[kc] = *(const half8*)(xbase + (size_t)1 * BB * HH + kc * 32);

        auto stepK = [&](int T, int cur, f32x4 (&accXc)[4], f32x4 (&accXn)[4]) {
            half8 a_h[4];
#pragma unroll
            for (int kc = 0; kc < 4; kc++)
                a_h[kc] = *(const half8*)&Hb[cur][rd_idx[kc]];
            f32x4 p[4], q[4];
#pragma unroll
            for (int gt = 0; gt < 4; gt++) {
                f32x4 t = __builtin_amdgcn_mfma_f32_16x16x32_f16(
                    a_h[0], whh[gt][0], accXc[gt], 0, 0, 0);
                p[gt] = __builtin_amdgcn_mfma_f32_16x16x32_f16(
                    a_h[1], whh[gt][1], t, 0, 0, 0);
                f32x4 u = __builtin_amdgcn_mfma_f32_16x16x32_f16(
                    a_h[2], whh[gt][2], (f32x4){0.f, 0.f, 0.f, 0.f}, 0, 0, 0);
                q[gt] = __builtin_amdgcn_mfma_f32_16x16x32_f16(
                    a_h[3], whh[gt][3], u, 0, 0, 0);
            }
#pragma unroll
            for (int gt = 0; gt < 4; gt++) {
                f32x4 t = bias_frag[gt];
#pragma unroll
                for (int kc = 0; kc < 4; kc++)
                    t = __builtin_amdgcn_mfma_f32_16x16x32_f16(
                        xcur[kc], wih[gt][kc], t, 0, 0, 0);
                accXn[gt] = t;
            }
            {
                const size_t tf =
                    (T + 2 < SS) ? (size_t)(T + 2) : (size_t)(SS - 1);
#pragma unroll
                for (int kc = 0; kc < 4; kc++)
                    xcur[kc] = *(const half8*)(xbase + tf * BB * HH + kc * 32);
            }
            finish(p, q, cur ^ 1);
        };
        for (int c = 0; c < NCH; c++) {
            if (c) {
                const int tgt = (c + 2) * CH;
                wait_src(tgt > SS ? SS : tgt);
            }
            for (int tt = 0; tt < CH; tt += 2) {
                stepK(c * CH + tt,     0, accXA, accXB);
                stepK(c * CH + tt + 1, 1, accXB, accXA);
            }
            signal(c);   // layers 1 AND 2 publish progress (fc consumes L2's)
        }
    }
}

extern "C" void kernel_launch(void* const* d_in, const int* in_sizes, int n_in,
                              void* d_out, int out_size, void* d_ws, size_t ws_size,
                              hipStream_t stream)
{
    (void)in_sizes; (void)n_in; (void)ws_size;
    const int*   text = (const int*)  d_in[0];
    const float* emb  = (const float*)d_in[1];
    const float* fcW  = (const float*)d_in[2];
    const float* fcb  = (const float*)d_in[3];
    const float* Wih0 = (const float*)d_in[4];
    const float* Whh0 = (const float*)d_in[5];
    const float* bih0 = (const float*)d_in[6];
    const float* bhh0 = (const float*)d_in[7];
    const float* Wih1 = (const float*)d_in[8];
    const float* Whh1 = (const float*)d_in[9];
    const float* bih1 = (const float*)d_in[10];
    const float* bhh1 = (const float*)d_in[11];
    const float* Wih2 = (const float*)d_in[12];
    const float* Whh2 = (const float*)d_in[13];
    const float* bih2 = (const float*)d_in[14];
    const float* bhh2 = (const float*)d_in[15];
    float* out = (float*)d_out;

    float* table = (float*)d_ws;
    _Float16* hX = (_Float16*)((char*)d_ws + 589824);
    _Float16* hY = hX + (size_t)SS * BB * HH;
    int* prog = ((int*)d_out) + ((size_t)out_size - 64);  // tail of out

    hipMemsetAsync(prog, 0, 64 * sizeof(int), stream);
    proj_kernel<<<VV, 512, 0, stream>>>(emb, Wih0, bih0, bhh0, table);
    lstm_pipe<<<NPIPE + NFC, 1024, 0, stream>>>(
        text, table, Whh0,
        Wih1, Whh1, bih1, bhh1,
        Wih2, Whh2, bih2, bhh2,
        hX, hY, fcW, fcb, out, prog);
}

// Round 14
// 4405.714 us; speedup vs baseline: 3.8016x; 3.8016x over previous
//
#include <hip/hip_runtime.h>
#include <cstddef>
#include <cstdint>

#define BB 256
#define SS 1024
#define VV 288
#define EE 100
#define HH 128
#define G4 512
#define CH 16
#define NCH (SS / CH)
#define NPIPE 48
#define NFC 2048

typedef _Float16 half8 __attribute__((ext_vector_type(8)));
typedef float f32x4 __attribute__((ext_vector_type(4)));
typedef float f32x2 __attribute__((ext_vector_type(2)));

__device__ __forceinline__ f32x2 exp2_2(f32x2 a) {
    f32x2 r;
    r[0] = __builtin_amdgcn_exp2f(a[0]);
    r[1] = __builtin_amdgcn_exp2f(a[1]);
    return r;
}
__device__ __forceinline__ f32x2 rcp_2(f32x2 a) {
    f32x2 r;
    r[0] = __builtin_amdgcn_rcpf(a[0]);
    r[1] = __builtin_amdgcn_rcpf(a[1]);
    return r;
}
__device__ __forceinline__ f32x2 vmin2(f32x2 a, float m) {
    f32x2 r;
    r[0] = fminf(a[0], m);
    r[1] = fminf(a[1], m);
    return r;
}

// LSTM elementwise for a row-pair; merged-rcp forms, total (inf-safe).
__device__ __forceinline__ f32x2 lstm_pair(
    f32x2 gi, f32x2 gf, f32x2 gg, f32x2 go, f32x2& cc)
{
    const float L1 = -1.4426950408889634f;   // -log2(e)
    const float L2 = -2.8853900817779268f;   // -2*log2(e)
    const f32x2 one = {1.0f, 1.0f};
    f32x2 ai = exp2_2(gi * L1);
    f32x2 bg = exp2_2(vmin2(gg * L2, 80.0f));
    f32x2 af = exp2_2(gf * L1);
    f32x2 sf = rcp_2(af + one);                       // sigmoid(f)
    f32x2 it = (one - bg) * rcp_2((ai + one) * (bg + one));
    cc = __builtin_elementwise_fma(sf, cc, it);       // c' = sf*c + it
    f32x2 dc = exp2_2(vmin2(cc * L2, 80.0f));
    f32x2 ao = exp2_2(go * L1);
    return (one - dc) * rcp_2((ao + one) * (dc + one));
}

// table[v][j] = bih0[j]+bhh0[j] + sum_e emb[v][e] * Wih0[j][e]   (fp32)
__global__ __launch_bounds__(512) void proj_kernel(
    const float* __restrict__ emb, const float* __restrict__ Wih0,
    const float* __restrict__ bih0, const float* __restrict__ bhh0,
    float* __restrict__ table)
{
    __shared__ float er[EE];
    const int v = blockIdx.x;
    const int j = threadIdx.x;
    for (int e = j; e < EE; e += 512) er[e] = emb[v * EE + e];
    __syncthreads();
    float acc = bih0[j] + bhh0[j];
    const float* wr = Wih0 + j * EE;
#pragma unroll 4
    for (int e = 0; e < EE; e++) acc = fmaf(er[e], wr[e], acc);
    table[v * G4 + j] = acc;
}

// ---- Fused 4-stage pipeline: blocks 0..47 = 3 LSTM layers x 16 tiles;
//      blocks 48..2095 = FC head tiles consuming layer-2 output per chunk.
__global__ __launch_bounds__(512)
__attribute__((amdgpu_waves_per_eu(2, 2)))
void lstm_pipe(const int* __restrict__ text, const float* __restrict__ table,
               const float* Whh0f,
               const float* Wih1f, const float* Whh1f,
               const float* __restrict__ bih1, const float* __restrict__ bhh1,
               const float* Wih2f, const float* Whh2f,
               const float* __restrict__ bih2, const float* __restrict__ bhh2,
               _Float16* hX, _Float16* hY,
               const float* __restrict__ fcW, const float* __restrict__ fcb,
               float* __restrict__ out, int* prog)
{
    __shared__ __align__(16) char shraw[73728];   // tokL(64K)+Hb(8K) | pfc
    const int tid = threadIdx.x;

    // ================= FC consumer blocks =================
    if (blockIdx.x >= NPIPE) {
        _Float16* pfc = (_Float16*)shraw;
        const int blk = blockIdx.x - NPIPE;
        // stage fcW -> f16 B-fragments in LDS (pack layout: f=nt*4+kc)
        for (int i = tid; i < 36864; i += 512) {
            const int e = i & 7;
            const int l = (i >> 3) & 63;
            const int f = i >> 9;
            const int kc = f & 3, nt = f >> 2;
            const int n = nt * 16 + (l & 15);
            const int k = kc * 32 + (l >> 4) * 8 + e;
            pfc[i] = (_Float16)fcW[n * HH + k];
        }
        __syncthreads();
        const int t = blk >> 1;              // timestep of this 128-row tile
        const int boff = (blk & 1) * 8;      // bt counters 0..7 or 8..15
        if (tid == 0) {
            for (int j = 0; j < 8; j++) {
                for (;;) {
                    int v = __hip_atomic_load(prog + 32 + boff + j,
                                              __ATOMIC_RELAXED,
                                              __HIP_MEMORY_SCOPE_AGENT);
                    // unsigned: float-bit clobber after completion reads done
                    if ((unsigned)v > (unsigned)t) break;
                    __builtin_amdgcn_s_sleep(64);
                }
            }
        }
        __syncthreads();
        {
            int v = __hip_atomic_load(prog + 32 + boff, __ATOMIC_ACQUIRE,
                                      __HIP_MEMORY_SCOPE_AGENT);
            asm volatile("" :: "v"(v));
        }
        const int wv = tid >> 6, l = tid & 63;
        const int colD = l & 15, qd = l >> 4;
        const size_t m0 = (size_t)blk * 128 + wv * 16;
        half8 a[4];
#pragma unroll
        for (int kc = 0; kc < 4; kc++)
            a[kc] = *(const half8*)(hX + (m0 + colD) * HH + kc * 32 + qd * 8);
        float fcb_r[18];
#pragma unroll
        for (int nt = 0; nt < 18; nt++) fcb_r[nt] = fcb[nt * 16 + colD];
#pragma unroll
        for (int nt = 0; nt < 18; nt++) {
            f32x4 acc = {0.f, 0.f, 0.f, 0.f};
#pragma unroll
            for (int kc = 0; kc < 4; kc++) {
                const half8 b =
                    *(const half8*)&pfc[(((nt * 4 + kc) << 6) + l) * 8];
                acc = __builtin_amdgcn_mfma_f32_16x16x32_f16(a[kc], b, acc,
                                                             0, 0, 0);
            }
#pragma unroll
            for (int r = 0; r < 4; r++)
                out[(m0 + 4 * qd + r) * VV + nt * 16 + colD] =
                    acc[r] + fcb_r[nt];
        }
        return;
    }

    // ================= LSTM pipeline blocks =================
    int* tokL = (int*)shraw;                               // 64 KB
    typedef _Float16 HbRow[2048];
    HbRow* Hb = (HbRow*)(shraw + 65536);                   // 8 KB dbuf
    const int w = tid >> 6, l = tid & 63;
    const int layer = blockIdx.x >> 4;
    const int bt = blockIdx.x & 15;
    const int B0 = bt * 16;
    const int colD = l & 15, qd = l >> 4;
    const int gcol = w * 16 + colD;

    const float* WhhF = (layer == 0) ? Whh0f : ((layer == 1) ? Whh1f : Whh2f);
    const float* WihF = (layer == 2) ? Wih2f : Wih1f;
    const float* bihp = (layer == 2) ? bih2 : bih1;
    const float* bhhp = (layer == 2) ? bhh2 : bhh1;
    const _Float16* xin = (layer == 1) ? hX : hY;
    _Float16* hout = (layer == 1) ? hY : hX;
    int* prog_src = prog + (layer - 1) * 16 + bt;
    int* prog_my  = prog + layer * 16 + bt;

    // Weight fragments straight from fp32 inputs (one-time)
    half8 whh[4][4], wih[4][4];
#pragma unroll
    for (int gt = 0; gt < 4; gt++)
#pragma unroll
        for (int kc = 0; kc < 4; kc++) {
            const int n = gt * 128 + gcol;
            const int k0 = kc * 32 + qd * 8;
            const float4 a0 = *(const float4*)(WhhF + (size_t)n * HH + k0);
            const float4 a1 = *(const float4*)(WhhF + (size_t)n * HH + k0 + 4);
            half8 hf;
            hf[0] = (_Float16)a0.x; hf[1] = (_Float16)a0.y;
            hf[2] = (_Float16)a0.z; hf[3] = (_Float16)a0.w;
            hf[4] = (_Float16)a1.x; hf[5] = (_Float16)a1.y;
            hf[6] = (_Float16)a1.z; hf[7] = (_Float16)a1.w;
            whh[gt][kc] = hf;
            if (layer) {
                const float4 b0 = *(const float4*)(WihF + (size_t)n * HH + k0);
                const float4 b1 = *(const float4*)(WihF + (size_t)n * HH + k0 + 4);
                half8 hg;
                hg[0] = (_Float16)b0.x; hg[1] = (_Float16)b0.y;
                hg[2] = (_Float16)b0.z; hg[3] = (_Float16)b0.w;
                hg[4] = (_Float16)b1.x; hg[5] = (_Float16)b1.y;
                hg[6] = (_Float16)b1.z; hg[7] = (_Float16)b1.w;
                wih[gt][kc] = hg;
            }
        }
    f32x4 bias_frag[4];
#pragma unroll
    for (int gt = 0; gt < 4; gt++) {
        float b = 0.0f;
        if (layer) {
            const int g = gt * 128 + gcol;
            b = bihp[g] + bhhp[g];
        }
        bias_frag[gt] = (f32x4){b, b, b, b};
    }
    if (layer == 0) {
        for (int kk = 0; kk < 32; kk++) {
            const int lin = kk * 512 + tid;
            const int b = lin >> 10, t = lin & 1023;
            tokL[t * 16 + b] = text[(((size_t)B0 + b) << 10) | t];
        }
    }
    for (int i = tid; i < 2048; i += 512) Hb[0][i] = (_Float16)0.0f;
    f32x2 c_acc0 = {0.f, 0.f}, c_acc1 = {0.f, 0.f};

    int rd_idx[4], wr_idx[4];
#pragma unroll
    for (int kc = 0; kc < 4; kc++)
        rd_idx[kc] = (colD * 128 + kc * 32 + qd * 8) ^ ((colD & 7) << 3);
#pragma unroll
    for (int r = 0; r < 4; r++) {
        const int rr = 4 * qd + r;
        wr_idx[r] = (rr * 128 + gcol) ^ ((rr & 7) << 3);
    }
    _Float16* houtp = hout + ((size_t)B0 + 4 * qd) * HH + gcol;
    __syncthreads();

    auto wait_src = [&](int target) {
        int v = __hip_atomic_load(prog_src, __ATOMIC_RELAXED,
                                  __HIP_MEMORY_SCOPE_AGENT);
        while (v < target) {
            __builtin_amdgcn_s_sleep(8);
            v = __hip_atomic_load(prog_src, __ATOMIC_RELAXED,
                                  __HIP_MEMORY_SCOPE_AGENT);
        }
        v = __hip_atomic_load(prog_src, __ATOMIC_ACQUIRE,
                              __HIP_MEMORY_SCOPE_AGENT);
        asm volatile("" :: "v"(v));
    };
    auto signal = [&](int c) {
        asm volatile("s_waitcnt vmcnt(0)" ::: "memory");
        __builtin_amdgcn_s_barrier();
        if (tid == 0) {
            __threadfence();
            __hip_atomic_store(prog_my, (c + 1) * CH, __ATOMIC_RELEASE,
                               __HIP_MEMORY_SCOPE_AGENT);
        }
    };
    // finish: p,q,r2,s are FOUR independent 1-deep h-chain partials.
    auto finish = [&](f32x4 (&p)[4], f32x4 (&q)[4], f32x4 (&r2)[4],
                      f32x4 (&s)[4], int nxt) {
        f32x4 acc[4];
#pragma unroll
        for (int gt = 0; gt < 4; gt++)
            acc[gt] = (p[gt] + q[gt]) + (r2[gt] + s[gt]);
        {
            f32x2 gi = {acc[0][0], acc[0][1]};
            f32x2 gf = {acc[1][0], acc[1][1]};
            f32x2 gg = {acc[2][0], acc[2][1]};
            f32x2 go = {acc[3][0], acc[3][1]};
            f32x2 hv = lstm_pair(gi, gf, gg, go, c_acc0);
            const _Float16 h0 = (_Float16)hv[0];
            const _Float16 h1 = (_Float16)hv[1];
            Hb[nxt][wr_idx[0]] = h0;
            Hb[nxt][wr_idx[1]] = h1;
            houtp[0 * HH] = h0;
            houtp[1 * HH] = h1;
        }
        {
            f32x2 gi = {acc[0][2], acc[0][3]};
            f32x2 gf = {acc[1][2], acc[1][3]};
            f32x2 gg = {acc[2][2], acc[2][3]};
            f32x2 go = {acc[3][2], acc[3][3]};
            f32x2 hv = lstm_pair(gi, gf, gg, go, c_acc1);
            const _Float16 h2 = (_Float16)hv[0];
            const _Float16 h3 = (_Float16)hv[1];
            Hb[nxt][wr_idx[2]] = h2;
            Hb[nxt][wr_idx[3]] = h3;
            houtp[2 * HH] = h2;
            houtp[3 * HH] = h3;
        }
        houtp += BB * HH;
        asm volatile("s_waitcnt lgkmcnt(0)" ::: "memory");
        __builtin_amdgcn_s_barrier();
    };

    if (layer == 0) {
        f32x4 xgA[4], xgB[4];
        {
            const int4 tk0 = *(const int4*)&tokL[4 * qd];
            const float* g0 = table + (size_t)tk0.x * G4 + gcol;
            const float* g1 = table + (size_t)tk0.y * G4 + gcol;
            const float* g2 = table + (size_t)tk0.z * G4 + gcol;
            const float* g3 = table + (size_t)tk0.w * G4 + gcol;
#pragma unroll
            for (int gt = 0; gt < 4; gt++) {
                xgA[gt][0] = g0[gt * 128];
                xgA[gt][1] = g1[gt * 128];
                xgA[gt][2] = g2[gt * 128];
                xgA[gt][3] = g3[gt * 128];
            }
        }
        auto step0 = [&](int T, int cur, f32x4 (&xgc)[4], f32x4 (&xgn)[4]) {
            half8 a_h[4];
#pragma unroll
            for (int kc = 0; kc < 4; kc++)
                a_h[kc] = *(const half8*)&Hb[cur][rd_idx[kc]];
            const int Tn = (T + 1 < SS) ? T + 1 : T;
            const int4 tkn = *(const int4*)&tokL[Tn * 16 + 4 * qd];
            f32x4 p[4], q[4], r2[4], s[4];
            const f32x4 z = {0.f, 0.f, 0.f, 0.f};
#pragma unroll
            for (int gt = 0; gt < 4; gt++) {
                p[gt]  = __builtin_amdgcn_mfma_f32_16x16x32_f16(
                    a_h[0], whh[gt][0], xgc[gt], 0, 0, 0);
                q[gt]  = __builtin_amdgcn_mfma_f32_16x16x32_f16(
                    a_h[1], whh[gt][1], z, 0, 0, 0);
                r2[gt] = __builtin_amdgcn_mfma_f32_16x16x32_f16(
                    a_h[2], whh[gt][2], z, 0, 0, 0);
                s[gt]  = __builtin_amdgcn_mfma_f32_16x16x32_f16(
                    a_h[3], whh[gt][3], z, 0, 0, 0);
            }
            {
                const float* g0 = table + (size_t)tkn.x * G4 + gcol;
                const float* g1 = table + (size_t)tkn.y * G4 + gcol;
                const float* g2 = table + (size_t)tkn.z * G4 + gcol;
                const float* g3 = table + (size_t)tkn.w * G4 + gcol;
#pragma unroll
                for (int gt = 0; gt < 4; gt++) {
                    xgn[gt][0] = g0[gt * 128];
                    xgn[gt][1] = g1[gt * 128];
                    xgn[gt][2] = g2[gt * 128];
                    xgn[gt][3] = g3[gt * 128];
                }
            }
            finish(p, q, r2, s, cur ^ 1);
        };
        for (int c = 0; c < NCH; c++) {
            for (int tt = 0; tt < CH; tt += 2) {
                step0(c * CH + tt,     0, xgA, xgB);
                step0(c * CH + tt + 1, 1, xgB, xgA);
            }
            signal(c);
        }
    } else {
        // fill: need x through step 1 for prologue => src >= CH+2 covers it
        wait_src(CH + 2);
        const _Float16* xbase = xin + ((size_t)B0 + colD) * HH + qd * 8;
        half8 xcur[4];
        f32x4 accXA[4], accXB[4];
#pragma unroll
        for (int kc = 0; kc < 4; kc++)
            xcur[kc] = *(const half8*)(xbase + (size_t)0 * BB * HH + kc * 32);
#pragma unroll
        for (int gt = 0; gt < 4; gt++) {
            f32x4 t = bias_frag[gt];
#pragma unroll
            for (int kc = 0; kc < 4; kc++)
                t = __builtin_amdgcn_mfma_f32_16x16x32_f16(
                    xcur[kc], wih[gt][kc], t, 0, 0, 0);
            accXA[gt] = t;
        }
#pragma unroll
        for (int kc = 0; kc < 4; kc++)
            xcur[kc] = *(const half8*)(xbase + (size_t)1 * BB * HH + kc * 32);

        auto stepK = [&](int T, int cur, f32x4 (&accXc)[4], f32x4 (&accXn)[4]) {
            half8 a_h[4];
#pragma unroll
            for (int kc = 0; kc < 4; kc++)
                a_h[kc] = *(const half8*)&Hb[cur][rd_idx[kc]];
            f32x4 p[4], q[4], r2[4], s[4];
            const f32x4 z = {0.f, 0.f, 0.f, 0.f};
#pragma unroll
            for (int gt = 0; gt < 4; gt++) {
                p[gt]  = __builtin_amdgcn_mfma_f32_16x16x32_f16(
                    a_h[0], whh[gt][0], accXc[gt], 0, 0, 0);
                q[gt]  = __builtin_amdgcn_mfma_f32_16x16x32_f16(
                    a_h[1], whh[gt][1], z, 0, 0, 0);
                r2[gt] = __builtin_amdgcn_mfma_f32_16x16x32_f16(
                    a_h[2], whh[gt][2], z, 0, 0, 0);
                s[gt]  = __builtin_amdgcn_mfma_f32_16x16x32_f16(
                    a_h[3], whh[gt][3], z, 0, 0, 0);
            }
#pragma unroll
            for (int gt = 0; gt < 4; gt++) {
                f32x4 t = bias_frag[gt];
#pragma unroll
                for (int kc = 0; kc < 4; kc++)
                    t = __builtin_amdgcn_mfma_f32_16x16x32_f16(
                        xcur[kc], wih[gt][kc], t, 0, 0, 0);
                accXn[gt] = t;
            }
            {
                const size_t tf =
                    (T + 2 < SS) ? (size_t)(T + 2) : (size_t)(SS - 1);
#pragma unroll
                for (int kc = 0; kc < 4; kc++)
                    xcur[kc] = *(const half8*)(xbase + tf * BB * HH + kc * 32);
            }
            finish(p, q, r2, s, cur ^ 1);
        };
        for (int c = 0; c < NCH; c++) {
            if (c) {
                // chunk c reads x up to (c+1)*CH+1 (incl. T+2 prefetch)
                const int tgt = (c + 1) * CH + 2;
                wait_src(tgt > SS ? SS : tgt);
            }
            for (int tt = 0; tt < CH; tt += 2) {
                stepK(c * CH + tt,     0, accXA, accXB);
                stepK(c * CH + tt + 1, 1, accXB, accXA);
            }
            signal(c);   // layers 1 AND 2 publish progress (fc consumes L2's)
        }
    }
}

extern "C" void kernel_launch(void* const* d_in, const int* in_sizes, int n_in,
                              void* d_out, int out_size, void* d_ws, size_t ws_size,
                              hipStream_t stream)
{
    (void)in_sizes; (void)n_in; (void)ws_size;
    const int*   text = (const int*)  d_in[0];
    const float* emb  = (const float*)d_in[1];
    const float* fcW  = (const float*)d_in[2];
    const float* fcb  = (const float*)d_in[3];
    const float* Wih0 = (const float*)d_in[4];
    const float* Whh0 = (const float*)d_in[5];
    const float* bih0 = (const float*)d_in[6];
    const float* bhh0 = (const float*)d_in[7];
    const float* Wih1 = (const float*)d_in[8];
    const float* Whh1 = (const float*)d_in[9];
    const float* bih1 = (const float*)d_in[10];
    const float* bhh1 = (const float*)d_in[11];
    const float* Wih2 = (const float*)d_in[12];
    const float* Whh2 = (const float*)d_in[13];
    const float* bih2 = (const float*)d_in[14];
    const float* bhh2 = (const float*)d_in[15];
    float* out = (float*)d_out;

    float* table = (float*)d_ws;
    _Float16* hX = (_Float16*)((char*)d_ws + 589824);
    _Float16* hY = hX + (size_t)SS * BB * HH;
    int* prog = ((int*)d_out) + ((size_t)out_size - 64);  // tail of out

    hipMemsetAsync(prog, 0, 64 * sizeof(int), stream);
    proj_kernel<<<VV, 512, 0, stream>>>(emb, Wih0, bih0, bhh0, table);
    lstm_pipe<<<NPIPE + NFC, 512, 0, stream>>>(
        text, table, Whh0,
        Wih1, Whh1, bih1, bhh1,
        Wih2, Whh2, bih2, bhh2,
        hX, hY, fcW, fcb, out, prog);
}

// Round 15
// 1512.684 us; speedup vs baseline: 11.0721x; 2.9125x over previous
//
#include <hip/hip_runtime.h>
#include <cstddef>
#include <cstdint>

#define BB 256
#define SS 1024
#define VV 288
#define EE 100
#define HH 128
#define G4 512
#define CH 16
#define NCH (SS / CH)
#define NPIPE 48
#define NFC 2048

typedef _Float16 half8 __attribute__((ext_vector_type(8)));
typedef float f32x4 __attribute__((ext_vector_type(4)));
typedef float f32x2 __attribute__((ext_vector_type(2)));

__device__ __forceinline__ f32x2 exp2_2(f32x2 a) {
    f32x2 r;
    r[0] = __builtin_amdgcn_exp2f(a[0]);
    r[1] = __builtin_amdgcn_exp2f(a[1]);
    return r;
}
__device__ __forceinline__ f32x2 rcp_2(f32x2 a) {
    f32x2 r;
    r[0] = __builtin_amdgcn_rcpf(a[0]);
    r[1] = __builtin_amdgcn_rcpf(a[1]);
    return r;
}
__device__ __forceinline__ f32x2 vmin2(f32x2 a, float m) {
    f32x2 r;
    r[0] = fminf(a[0], m);
    r[1] = fminf(a[1], m);
    return r;
}

// LSTM elementwise for a row-pair; merged-rcp forms, total (inf-safe).
__device__ __forceinline__ f32x2 lstm_pair(
    f32x2 gi, f32x2 gf, f32x2 gg, f32x2 go, f32x2& cc)
{
    const float L1 = -1.4426950408889634f;   // -log2(e)
    const float L2 = -2.8853900817779268f;   // -2*log2(e)
    const f32x2 one = {1.0f, 1.0f};
    f32x2 ai = exp2_2(gi * L1);
    f32x2 bg = exp2_2(vmin2(gg * L2, 80.0f));
    f32x2 af = exp2_2(gf * L1);
    f32x2 sf = rcp_2(af + one);                       // sigmoid(f)
    f32x2 it = (one - bg) * rcp_2((ai + one) * (bg + one));
    cc = __builtin_elementwise_fma(sf, cc, it);       // c' = sf*c + it
    f32x2 dc = exp2_2(vmin2(cc * L2, 80.0f));
    f32x2 ao = exp2_2(go * L1);
    return (one - dc) * rcp_2((ao + one) * (dc + one));
}

// table[v][j] = bih0[j]+bhh0[j] + sum_e emb[v][e] * Wih0[j][e]   (fp32)
__global__ __launch_bounds__(512) void proj_kernel(
    const float* __restrict__ emb, const float* __restrict__ Wih0,
    const float* __restrict__ bih0, const float* __restrict__ bhh0,
    float* __restrict__ table)
{
    __shared__ float er[EE];
    const int v = blockIdx.x;
    const int j = threadIdx.x;
    for (int e = j; e < EE; e += 512) er[e] = emb[v * EE + e];
    __syncthreads();
    float acc = bih0[j] + bhh0[j];
    const float* wr = Wih0 + j * EE;
#pragma unroll 4
    for (int e = 0; e < EE; e++) acc = fmaf(er[e], wr[e], acc);
    table[v * G4 + j] = acc;
}

// ---- Fused 4-stage pipeline: blocks 0..47 = 3 LSTM layers x 16 tiles;
//      blocks 48..2095 = FC head tiles consuming layer-2 output per chunk.
__global__ __launch_bounds__(512)
__attribute__((amdgpu_waves_per_eu(2, 2)))
void lstm_pipe(const int* __restrict__ text, const float* __restrict__ table,
               const float* Whh0f,
               const float* Wih1f, const float* Whh1f,
               const float* __restrict__ bih1, const float* __restrict__ bhh1,
               const float* Wih2f, const float* Whh2f,
               const float* __restrict__ bih2, const float* __restrict__ bhh2,
               _Float16* hX, _Float16* hY,
               const float* __restrict__ fcW, const float* __restrict__ fcb,
               float* __restrict__ out, int* prog)
{
    __shared__ __align__(16) char shraw[73728];   // tokL(64K)+Hb(8K) | pfc
    const int tid = threadIdx.x;

    // ================= FC consumer blocks =================
    if (blockIdx.x >= NPIPE) {
        _Float16* pfc = (_Float16*)shraw;
        const int blk = blockIdx.x - NPIPE;
        // stage fcW -> f16 B-fragments in LDS (pack layout: f=nt*4+kc)
        for (int i = tid; i < 36864; i += 512) {
            const int e = i & 7;
            const int l = (i >> 3) & 63;
            const int f = i >> 9;
            const int kc = f & 3, nt = f >> 2;
            const int n = nt * 16 + (l & 15);
            const int k = kc * 32 + (l >> 4) * 8 + e;
            pfc[i] = (_Float16)fcW[n * HH + k];
        }
        __syncthreads();
        const int t = blk >> 1;              // timestep of this 128-row tile
        const int boff = (blk & 1) * 8;      // bt counters 0..7 or 8..15
        if (tid == 0) {
            for (int j = 0; j < 8; j++) {
                for (;;) {
                    int v = __hip_atomic_load(prog + 32 + boff + j,
                                              __ATOMIC_RELAXED,
                                              __HIP_MEMORY_SCOPE_AGENT);
                    // unsigned: float-bit clobber after completion reads done
                    if ((unsigned)v > (unsigned)t) break;
                    __builtin_amdgcn_s_sleep(64);
                }
            }
        }
        __syncthreads();
        {
            int v = __hip_atomic_load(prog + 32 + boff, __ATOMIC_ACQUIRE,
                                      __HIP_MEMORY_SCOPE_AGENT);
            asm volatile("" :: "v"(v));
        }
        const int wv = tid >> 6, l = tid & 63;
        const int colD = l & 15, qd = l >> 4;
        const size_t m0 = (size_t)blk * 128 + wv * 16;
        half8 a[4];
#pragma unroll
        for (int kc = 0; kc < 4; kc++)
            a[kc] = *(const half8*)(hX + (m0 + colD) * HH + kc * 32 + qd * 8);
        float fcb_r[18];
#pragma unroll
        for (int nt = 0; nt < 18; nt++) fcb_r[nt] = fcb[nt * 16 + colD];
#pragma unroll
        for (int nt = 0; nt < 18; nt++) {
            f32x4 acc = {0.f, 0.f, 0.f, 0.f};
#pragma unroll
            for (int kc = 0; kc < 4; kc++) {
                const half8 b =
                    *(const half8*)&pfc[(((nt * 4 + kc) << 6) + l) * 8];
                acc = __builtin_amdgcn_mfma_f32_16x16x32_f16(a[kc], b, acc,
                                                             0, 0, 0);
            }
#pragma unroll
            for (int r = 0; r < 4; r++)
                out[(m0 + 4 * qd + r) * VV + nt * 16 + colD] =
                    acc[r] + fcb_r[nt];
        }
        return;
    }

    // ================= LSTM pipeline blocks (r11-proven) =================
    int* tokL = (int*)shraw;                               // 64 KB
    typedef _Float16 HbRow[2048];
    HbRow* Hb = (HbRow*)(shraw + 65536);                   // 8 KB dbuf
    const int w = tid >> 6, l = tid & 63;
    const int layer = blockIdx.x >> 4;
    const int bt = blockIdx.x & 15;
    const int B0 = bt * 16;
    const int colD = l & 15, qd = l >> 4;
    const int gcol = w * 16 + colD;

    const float* WhhF = (layer == 0) ? Whh0f : ((layer == 1) ? Whh1f : Whh2f);
    const float* WihF = (layer == 2) ? Wih2f : Wih1f;
    const float* bihp = (layer == 2) ? bih2 : bih1;
    const float* bhhp = (layer == 2) ? bhh2 : bhh1;
    const _Float16* xin = (layer == 1) ? hX : hY;
    _Float16* hout = (layer == 1) ? hY : hX;
    int* prog_src = prog + (layer - 1) * 16 + bt;
    int* prog_my  = prog + layer * 16 + bt;

    // Weight fragments straight from fp32 inputs (one-time)
    half8 whh[4][4], wih[4][4];
#pragma unroll
    for (int gt = 0; gt < 4; gt++)
#pragma unroll
        for (int kc = 0; kc < 4; kc++) {
            const int n = gt * 128 + gcol;
            const int k0 = kc * 32 + qd * 8;
            const float4 a0 = *(const float4*)(WhhF + (size_t)n * HH + k0);
            const float4 a1 = *(const float4*)(WhhF + (size_t)n * HH + k0 + 4);
            half8 hf;
            hf[0] = (_Float16)a0.x; hf[1] = (_Float16)a0.y;
            hf[2] = (_Float16)a0.z; hf[3] = (_Float16)a0.w;
            hf[4] = (_Float16)a1.x; hf[5] = (_Float16)a1.y;
            hf[6] = (_Float16)a1.z; hf[7] = (_Float16)a1.w;
            whh[gt][kc] = hf;
            if (layer) {
                const float4 b0 = *(const float4*)(WihF + (size_t)n * HH + k0);
                const float4 b1 = *(const float4*)(WihF + (size_t)n * HH + k0 + 4);
                half8 hg;
                hg[0] = (_Float16)b0.x; hg[1] = (_Float16)b0.y;
                hg[2] = (_Float16)b0.z; hg[3] = (_Float16)b0.w;
                hg[4] = (_Float16)b1.x; hg[5] = (_Float16)b1.y;
                hg[6] = (_Float16)b1.z; hg[7] = (_Float16)b1.w;
                wih[gt][kc] = hg;
            }
        }
    f32x4 bias_frag[4];
#pragma unroll
    for (int gt = 0; gt < 4; gt++) {
        float b = 0.0f;
        if (layer) {
            const int g = gt * 128 + gcol;
            b = bihp[g] + bhhp[g];
        }
        bias_frag[gt] = (f32x4){b, b, b, b};
    }
    if (layer == 0) {
        for (int kk = 0; kk < 32; kk++) {
            const int lin = kk * 512 + tid;
            const int b = lin >> 10, t = lin & 1023;
            tokL[t * 16 + b] = text[(((size_t)B0 + b) << 10) | t];
        }
    }
    for (int i = tid; i < 2048; i += 512) Hb[0][i] = (_Float16)0.0f;
    f32x2 c_acc0 = {0.f, 0.f}, c_acc1 = {0.f, 0.f};

    int rd_idx[4], wr_idx[4];
#pragma unroll
    for (int kc = 0; kc < 4; kc++)
        rd_idx[kc] = (colD * 128 + kc * 32 + qd * 8) ^ ((colD & 7) << 3);
#pragma unroll
    for (int r = 0; r < 4; r++) {
        const int rr = 4 * qd + r;
        wr_idx[r] = (rr * 128 + gcol) ^ ((rr & 7) << 3);
    }
    _Float16* houtp = hout + ((size_t)B0 + 4 * qd) * HH + gcol;
    __syncthreads();

    auto wait_src = [&](int target) {
        int v = __hip_atomic_load(prog_src, __ATOMIC_RELAXED,
                                  __HIP_MEMORY_SCOPE_AGENT);
        while (v < target) {
            __builtin_amdgcn_s_sleep(8);
            v = __hip_atomic_load(prog_src, __ATOMIC_RELAXED,
                                  __HIP_MEMORY_SCOPE_AGENT);
        }
        v = __hip_atomic_load(prog_src, __ATOMIC_ACQUIRE,
                              __HIP_MEMORY_SCOPE_AGENT);
        asm volatile("" :: "v"(v));
    };
    auto signal = [&](int c) {
        asm volatile("s_waitcnt vmcnt(0)" ::: "memory");
        __builtin_amdgcn_s_barrier();
        if (tid == 0) {
            __threadfence();
            __hip_atomic_store(prog_my, (c + 1) * CH, __ATOMIC_RELEASE,
                               __HIP_MEMORY_SCOPE_AGENT);
        }
    };
    auto finish = [&](f32x4 (&p)[4], f32x4 (&q)[4], int nxt) {
        f32x4 acc[4];
#pragma unroll
        for (int gt = 0; gt < 4; gt++) acc[gt] = p[gt] + q[gt];
        {
            f32x2 gi = {acc[0][0], acc[0][1]};
            f32x2 gf = {acc[1][0], acc[1][1]};
            f32x2 gg = {acc[2][0], acc[2][1]};
            f32x2 go = {acc[3][0], acc[3][1]};
            f32x2 hv = lstm_pair(gi, gf, gg, go, c_acc0);
            const _Float16 h0 = (_Float16)hv[0];
            const _Float16 h1 = (_Float16)hv[1];
            Hb[nxt][wr_idx[0]] = h0;
            Hb[nxt][wr_idx[1]] = h1;
            houtp[0 * HH] = h0;
            houtp[1 * HH] = h1;
        }
        {
            f32x2 gi = {acc[0][2], acc[0][3]};
            f32x2 gf = {acc[1][2], acc[1][3]};
            f32x2 gg = {acc[2][2], acc[2][3]};
            f32x2 go = {acc[3][2], acc[3][3]};
            f32x2 hv = lstm_pair(gi, gf, gg, go, c_acc1);
            const _Float16 h2 = (_Float16)hv[0];
            const _Float16 h3 = (_Float16)hv[1];
            Hb[nxt][wr_idx[2]] = h2;
            Hb[nxt][wr_idx[3]] = h3;
            houtp[2 * HH] = h2;
            houtp[3 * HH] = h3;
        }
        houtp += BB * HH;
        asm volatile("s_waitcnt lgkmcnt(0)" ::: "memory");
        __builtin_amdgcn_s_barrier();
    };

    if (layer == 0) {
        f32x4 xgA[4], xgB[4];
        {
            const int4 tk0 = *(const int4*)&tokL[4 * qd];
            const float* g0 = table + (size_t)tk0.x * G4 + gcol;
            const float* g1 = table + (size_t)tk0.y * G4 + gcol;
            const float* g2 = table + (size_t)tk0.z * G4 + gcol;
            const float* g3 = table + (size_t)tk0.w * G4 + gcol;
#pragma unroll
            for (int gt = 0; gt < 4; gt++) {
                xgA[gt][0] = g0[gt * 128];
                xgA[gt][1] = g1[gt * 128];
                xgA[gt][2] = g2[gt * 128];
                xgA[gt][3] = g3[gt * 128];
            }
        }
        auto step0 = [&](int T, int cur, f32x4 (&xgc)[4], f32x4 (&xgn)[4]) {
            half8 a_h[4];
#pragma unroll
            for (int kc = 0; kc < 4; kc++)
                a_h[kc] = *(const half8*)&Hb[cur][rd_idx[kc]];
            const int Tn = (T + 1 < SS) ? T + 1 : T;
            const int4 tkn = *(const int4*)&tokL[Tn * 16 + 4 * qd];
            f32x4 p[4], q[4];
#pragma unroll
            for (int gt = 0; gt < 4; gt++) {
                f32x4 t = __builtin_amdgcn_mfma_f32_16x16x32_f16(
                    a_h[0], whh[gt][0], xgc[gt], 0, 0, 0);
                p[gt] = __builtin_amdgcn_mfma_f32_16x16x32_f16(
                    a_h[1], whh[gt][1], t, 0, 0, 0);
                f32x4 u = __builtin_amdgcn_mfma_f32_16x16x32_f16(
                    a_h[2], whh[gt][2], (f32x4){0.f, 0.f, 0.f, 0.f}, 0, 0, 0);
                q[gt] = __builtin_amdgcn_mfma_f32_16x16x32_f16(
                    a_h[3], whh[gt][3], u, 0, 0, 0);
            }
            {
                const float* g0 = table + (size_t)tkn.x * G4 + gcol;
                const float* g1 = table + (size_t)tkn.y * G4 + gcol;
                const float* g2 = table + (size_t)tkn.z * G4 + gcol;
                const float* g3 = table + (size_t)tkn.w * G4 + gcol;
#pragma unroll
                for (int gt = 0; gt < 4; gt++) {
                    xgn[gt][0] = g0[gt * 128];
                    xgn[gt][1] = g1[gt * 128];
                    xgn[gt][2] = g2[gt * 128];
                    xgn[gt][3] = g3[gt * 128];
                }
            }
            finish(p, q, cur ^ 1);
        };
        for (int c = 0; c < NCH; c++) {
            for (int tt = 0; tt < CH; tt += 2) {
                step0(c * CH + tt,     0, xgA, xgB);
                step0(c * CH + tt + 1, 1, xgB, xgA);
            }
            signal(c);
        }
    } else {
        wait_src(2 * CH);
        const _Float16* xbase = xin + ((size_t)B0 + colD) * HH + qd * 8;
        half8 xcur[4];
        f32x4 accXA[4], accXB[4];
#pragma unroll
        for (int kc = 0; kc < 4; kc++)
            xcur[kc] = *(const half8*)(xbase + (size_t)0 * BB * HH + kc * 32);
#pragma unroll
        for (int gt = 0; gt < 4; gt++) {
            f32x4 t = bias_frag[gt];
#pragma unroll
            for (int kc = 0; kc < 4; kc++)
                t = __builtin_amdgcn_mfma_f32_16x16x32_f16(
                    xcur[kc], wih[gt][kc], t, 0, 0, 0);
            accXA[gt] = t;
        }
#pragma unroll
        for (int kc = 0; kc < 4; kc++)
            xcur[kc] = *(const half8*)(xbase + (size_t)1 * BB * HH + kc * 32);

        auto stepK = [&](int T, int cur, f32x4 (&accXc)[4], f32x4 (&accXn)[4]) {
            half8 a_h[4];
#pragma unroll
            for (int kc = 0; kc < 4; kc++)
                a_h[kc] = *(const half8*)&Hb[cur][rd_idx[kc]];
            f32x4 p[4], q[4];
#pragma unroll
            for (int gt = 0; gt < 4; gt++) {
                f32x4 t = __builtin_amdgcn_mfma_f32_16x16x32_f16(
                    a_h[0], whh[gt][0], accXc[gt], 0, 0, 0);
                p[gt] = __builtin_amdgcn_mfma_f32_16x16x32_f16(
                    a_h[1], whh[gt][1], t, 0, 0, 0);
                f32x4 u = __builtin_amdgcn_mfma_f32_16x16x32_f16(
                    a_h[2], whh[gt][2], (f32x4){0.f, 0.f, 0.f, 0.f}, 0, 0, 0);
                q[gt] = __builtin_amdgcn_mfma_f32_16x16x32_f16(
                    a_h[3], whh[gt][3], u, 0, 0, 0);
            }
#pragma unroll
            for (int gt = 0; gt < 4; gt++) {
                f32x4 t = bias_frag[gt];
#pragma unroll
                for (int kc = 0; kc < 4; kc++)
                    t = __builtin_amdgcn_mfma_f32_16x16x32_f16(
                        xcur[kc], wih[gt][kc], t, 0, 0, 0);
                accXn[gt] = t;
            }
            {
                const size_t tf =
                    (T + 2 < SS) ? (size_t)(T + 2) : (size_t)(SS - 1);
#pragma unroll
                for (int kc = 0; kc < 4; kc++)
                    xcur[kc] = *(const half8*)(xbase + tf * BB * HH + kc * 32);
            }
            finish(p, q, cur ^ 1);
        };
        for (int c = 0; c < NCH; c++) {
            if (c) {
                const int tgt = (c + 2) * CH;
                wait_src(tgt > SS ? SS : tgt);
            }
            for (int tt = 0; tt < CH; tt += 2) {
                stepK(c * CH + tt,     0, accXA, accXB);
                stepK(c * CH + tt + 1, 1, accXB, accXA);
            }
            signal(c);   // layers 1 AND 2 publish progress (fc consumes L2's)
        }
    }
}

extern "C" void kernel_launch(void* const* d_in, const int* in_sizes, int n_in,
                              void* d_out, int out_size, void* d_ws, size_t ws_size,
                              hipStream_t stream)
{
    (void)in_sizes; (void)n_in; (void)ws_size;
    const int*   text = (const int*)  d_in[0];
    const float* emb  = (const float*)d_in[1];
    const float* fcW  = (const float*)d_in[2];
    const float* fcb  = (const float*)d_in[3];
    const float* Wih0 = (const float*)d_in[4];
    const float* Whh0 = (const float*)d_in[5];
    const float* bih0 = (const float*)d_in[6];
    const float* bhh0 = (const float*)d_in[7];
    const float* Wih1 = (const float*)d_in[8];
    const float* Whh1 = (const float*)d_in[9];
    const float* bih1 = (const float*)d_in[10];
    const float* bhh1 = (const float*)d_in[11];
    const float* Wih2 = (const float*)d_in[12];
    const float* Whh2 = (const float*)d_in[13];
    const float* bih2 = (const float*)d_in[14];
    const float* bhh2 = (const float*)d_in[15];
    float* out = (float*)d_out;

    float* table = (float*)d_ws;
    _Float16* hX = (_Float16*)((char*)d_ws + 589824);
    _Float16* hY = hX + (size_t)SS * BB * HH;
    int* prog = ((int*)d_out) + ((size_t)out_size - 64);  // tail of out

    hipMemsetAsync(prog, 0, 64 * sizeof(int), stream);
    proj_kernel<<<VV, 512, 0, stream>>>(emb, Wih0, bih0, bhh0, table);
    lstm_pipe<<<NPIPE + NFC, 512, 0, stream>>>(
        text, table, Whh0,
        Wih1, Whh1, bih1, bhh1,
        Wih2, Whh2, bih2, bhh2,
        hX, hY, fcW, fcb, out, prog);
}